// Round 9
// baseline (15997.237 us; speedup 1.0000x reference)
//
#include <hip/hip_runtime.h>
#include <hip/hip_bf16.h>

#define B_ 64
#define T_ 512
#define D_ 256
#define H_ 1024
#define RING 64          // h-history ring depth (slot reuse after 64 steps)
#define NBLK 128         // blocks per layer
#define JG 8             // h-cols per block

typedef __attribute__((ext_vector_type(8))) short short8;
typedef __attribute__((ext_vector_type(4))) float floatx4;

__device__ __forceinline__ unsigned short f2bf(float f){
  unsigned u = __builtin_bit_cast(unsigned, f);
  u = (u + 0x7fffu + ((u >> 16) & 1u)) >> 16;
  return (unsigned short)u;
}
__device__ __forceinline__ short8 pack8(floatx4 a, floatx4 b){
  short8 r;
  r[0]=(short)f2bf(a[0]); r[1]=(short)f2bf(a[1]); r[2]=(short)f2bf(a[2]); r[3]=(short)f2bf(a[3]);
  r[4]=(short)f2bf(b[0]); r[5]=(short)f2bf(b[1]); r[6]=(short)f2bf(b[2]); r[7]=(short)f2bf(b[3]);
  return r;
}
__device__ __forceinline__ float sigm(float v){ return 1.f/(1.f+__expf(-v)); }
__device__ __forceinline__ float tanh_f(float v){ return 1.f - 2.f/(1.f+__expf(2.f*v)); }

// LAYER 0: K = 256 (x, fp32) + 1024 (h0) = 1280.  LAYER 1: K = 1024 (h0) + 1024 (h1) = 2048.
// Block: 512 thr = 8 waves = 8 K-slices; owns 8 h-cols (32 gate rows), all 64 batch rows.
// Weights/wave: 2 n-tiles x NK ks = 64 (L1) / 40 (L0) VGPRs -> headroom for in-flight A-loads.
template<int LAYER>
__device__ __forceinline__ void run_lstm(
    const float* __restrict__ x,
    const float* __restrict__ Wi, const float* __restrict__ Wh,
    const float* __restrict__ bi, const float* __restrict__ bh_,
    unsigned* pairs, unsigned short* h0r, unsigned short* h1r, float* h1f,
    int jbase, int myblk,
    float* partial /*[4][64][33]*/, float* c_st /*[64][8]*/, float* biasv /*[32]*/)
{
  constexpr int KTOT = LAYER ? 2048 : 1280;
  constexpr int KW   = KTOT/8;            // per-wave K slice (256 / 160)
  constexpr int NK   = KW/32;             // k-steps per wave (8 / 5)
  constexpr int KA   = LAYER ? 1024 : 256;   // Wi K extent (h part starts here)
  constexpr int KD   = LAYER ? H_ : D_;      // Wi inner dim

  const int tid  = threadIdx.x;
  const int wv   = tid >> 6;              // K-slice 0..7
  const int lane = tid & 63;
  const int n15  = lane & 15;
  const int rowq = lane >> 4;             // 0..3
  const int kq8  = rowq * 8;

  // ---- one-time: weights -> registers (bf16); n = nt*16+n15 in [0,32): gate q=n>>3, col jj=n&7
  short8 bfr[2][NK];
  #pragma unroll
  for (int nt = 0; nt < 2; nt++){
    int n = nt*16 + n15;
    int wrow = (n >> 3)*H_ + jbase + (n & 7);
    #pragma unroll
    for (int ks = 0; ks < NK; ks++){
      int k = wv*KW + ks*32 + kq8;
      const float* s = (k < KA) ? (Wi + (size_t)wrow*KD + k)
                                : (Wh + (size_t)wrow*H_ + (k - KA));
      bfr[nt][ks] = pack8(*(const floatx4*)s, *(const floatx4*)(s + 4));
    }
  }
  if (tid < 32){
    int col = (tid >> 3)*H_ + jbase + (tid & 7);
    biasv[tid] = bi[col] + bh_[col];
  }
  if (tid < 512) c_st[tid] = 0.f;          // [64][8]
  for (int i = tid; i < 4*64*33; i += 512) partial[i] = 0.f;
  __syncthreads();

  // every wave polls: lane l watches producers 2l and 2l+1 (128 per layer)
  unsigned long long* pr64 = (unsigned long long*)pairs;

  for (int t = 0; t < T_; t++){
    floatx4 acc[4][2];
    #pragma unroll
    for (int mt = 0; mt < 4; mt++)
      #pragma unroll
      for (int nt = 0; nt < 2; nt++)
        acc[mt][nt] = (floatx4)0.f;

    // ---- L0: x-part (k<256) loads + MFMAs hoisted before the wait (input-independent)
    if constexpr (LAYER == 0){
      #pragma unroll
      for (int ks = 0; ks < NK; ks++){
        const int kb = wv*KW + ks*32;
        if (kb >= 256) continue;           // wave-uniform
        const int kk = kb + kq8;
        short8 ax[4];
        #pragma unroll
        for (int mt = 0; mt < 4; mt++){
          const float* xs = x + ((size_t)(mt*16 + n15)*T_ + t)*D_ + kk;
          ax[mt] = pack8(*(const floatx4*)xs, *(const floatx4*)(xs+4));
        }
        #pragma unroll
        for (int mt = 0; mt < 4; mt++)
          #pragma unroll
          for (int nt = 0; nt < 2; nt++)
            acc[mt][nt] = __builtin_amdgcn_mfma_f32_16x16x32_bf16(ax[mt], bfr[nt][ks], acc[mt][nt], 0, 0, 0);
      }
    }

    // ---- dataflow wait (unmasked; relaxed agent polls)
    {
      unsigned tgt0, tgt1;
      if (LAYER == 0){ tgt0 = (unsigned)t; tgt1 = (t >= RING) ? (unsigned)(t-RING+1) : 0u; }
      else           { tgt0 = (unsigned)(t+1); tgt1 = (unsigned)t; }
      if (tgt0 | tgt1){
        long g = 0;
        for (;;){
          unsigned long long a = __hip_atomic_load(pr64 + 2*lane,     __ATOMIC_RELAXED, __HIP_MEMORY_SCOPE_AGENT);
          unsigned long long b = __hip_atomic_load(pr64 + 2*lane + 1, __ATOMIC_RELAXED, __HIP_MEMORY_SCOPE_AGENT);
          bool ok = ((unsigned)a >= tgt0) && ((unsigned)(a>>32) >= tgt1)
                 && ((unsigned)b >= tgt0) && ((unsigned)(b>>32) >= tgt1);
          if (__all(ok)) break;
          __builtin_amdgcn_s_sleep(2);
          if (++g > (1L<<22)) break;   // safety valve; never hit in correct runs
        }
      }
    }

    const unsigned short* h0t = h0r + (size_t)((LAYER ? t : (t-1)) & (RING-1)) * (B_*H_);
    const unsigned short* h1t = h1r + (size_t)((t-1) & (RING-1)) * (B_*H_);

    #pragma unroll
    for (int ks = 0; ks < NK; ks++){
      const int kb = wv*KW + ks*32;
      if (LAYER == 0 && kb < 256) continue;   // x part hoisted above
      if (kb >= KA && t == 0) continue;       // h[-1] = 0 (wave-uniform)
      const int kk = kb + kq8;
      const unsigned short* base;
      if constexpr (LAYER == 0) base = h0t + (kk - 256);
      else                      base = (kb < 1024) ? (h0t + kk) : (h1t + (kk - 1024));
      short8 afr[4];
      #pragma unroll
      for (int mt = 0; mt < 4; mt++)
        afr[mt] = *(const short8*)(base + (size_t)(mt*16 + n15)*H_);
      #pragma unroll
      for (int mt = 0; mt < 4; mt++)
        #pragma unroll
        for (int nt = 0; nt < 2; nt++)
          acc[mt][nt] = __builtin_amdgcn_mfma_f32_16x16x32_bf16(afr[mt], bfr[nt][ks], acc[mt][nt], 0, 0, 0);
    }

    // ---- cross-wave K-reduction: waves w and w+4 share slot w&3 (exactly 2-way atomic collisions)
    #pragma unroll
    for (int mt = 0; mt < 4; mt++)
      #pragma unroll
      for (int nt = 0; nt < 2; nt++)
        #pragma unroll
        for (int r = 0; r < 4; r++){
          int b = mt*16 + rowq*4 + r;      // C layout: row=(lane>>4)*4+r
          int n = nt*16 + n15;             // col=lane&15
          atomicAdd(&partial[(((wv & 3)*64) + b)*33 + n], acc[mt][nt][r]);
        }
    __syncthreads();

    // ---- epilogue: reduce 4 slots + bias -> gates -> (c,h); re-zero partial; h store
    if (tid < 256){
      int b = tid >> 2, jj0 = (tid & 3)*2;
      unsigned short hb[2]; float hf[2];
      #pragma unroll
      for (int u = 0; u < 2; u++){
        int jj = jj0 + u;
        float g[4];
        #pragma unroll
        for (int q = 0; q < 4; q++){
          int n = q*8 + jj;
          float s = 0.f;
          #pragma unroll
          for (int w = 0; w < 4; w++){
            s += partial[(w*64 + b)*33 + n];
            partial[(w*64 + b)*33 + n] = 0.f;
          }
          g[q] = s + biasv[n];
        }
        float co = c_st[b*8 + jj];
        float si = sigm(g[0]), sf = sigm(g[1]), tg = tanh_f(g[2]), so = sigm(g[3]);
        float cn = sf*co + si*tg;
        float hn = so*tanh_f(cn);
        c_st[b*8 + jj] = cn;
        hb[u] = f2bf(hn); hf[u] = hn;
      }
      unsigned pk = (unsigned)hb[0] | ((unsigned)hb[1] << 16);
      unsigned short* dst = (LAYER ? h1r : h0r)
                          + (size_t)(t & (RING-1))*(B_*H_) + (size_t)b*H_ + jbase + jj0;
      __hip_atomic_store((unsigned*)dst, pk, __ATOMIC_RELAXED, __HIP_MEMORY_SCOPE_AGENT);
      if (LAYER == 1 && t == T_-1){
        h1f[(size_t)b*H_ + jbase + jj0]     = hf[0];
        h1f[(size_t)b*H_ + jbase + jj0 + 1] = hf[1];
      }
    }
    __syncthreads();   // drains vmcnt in every wave (h stores + re-zero visible) before the post
    if (tid == 0)
      __hip_atomic_store(pairs + 2*myblk + LAYER, (unsigned)(t+1),
                         __ATOMIC_RELAXED, __HIP_MEMORY_SCOPE_AGENT);
  }
}

__global__ __launch_bounds__(512, 2) void lstm_pk(
    const float* __restrict__ x,
    const float* __restrict__ Wih0, const float* __restrict__ Whh0,
    const float* __restrict__ bih0, const float* __restrict__ bhh0,
    const float* __restrict__ Wih1, const float* __restrict__ Whh1,
    const float* __restrict__ bih1, const float* __restrict__ bhh1,
    char* __restrict__ ws)
{
  __shared__ float partial[4*64*33];   // 33.8 KB, zero-maintained, 2-way atomic reduce
  __shared__ float c_st[512];          // [64 batch][8 cols]
  __shared__ float biasv[32];

  unsigned* pairs     = (unsigned*)ws;                                    // [128][2] = (f0,f1) per jgroup, 1 KB
  unsigned short* h0r = (unsigned short*)(ws + (1<<20));                  // RING x [64][1024] bf16 (8 MB)
  unsigned short* h1r = (unsigned short*)(ws + (1<<20) + RING*B_*H_*2);   // 8 MB
  float* h1f          = (float*)(ws + (1<<20) + 2*(size_t)RING*B_*H_*2);  // [64][1024] fp32

  const int bid = blockIdx.x;
  if (bid < NBLK)
    run_lstm<0>(x, Wih0, Whh0, bih0, bhh0, pairs, h0r, h1r, h1f, bid*JG, bid, partial, c_st, biasv);
  else
    run_lstm<1>(x, Wih1, Whh1, bih1, bhh1, pairs, h0r, h1r, h1f, (bid-NBLK)*JG, bid-NBLK, partial, c_st, biasv);
}

__global__ __launch_bounds__(128) void fc_k(
    const float* __restrict__ h1f, const float* __restrict__ Wfc,
    const float* __restrict__ bfc, float* __restrict__ out)
{
  __shared__ float hv[1024];
  int b = blockIdx.x, c = threadIdx.x;
  for (int i = c; i < 1024; i += 128) hv[i] = h1f[(size_t)b*1024 + i];
  __syncthreads();
  const floatx4* w4 = (const floatx4*)(Wfc + (size_t)c*1024);
  const floatx4* h4 = (const floatx4*)hv;
  float acc = 0.f;
  #pragma unroll 8
  for (int k = 0; k < 256; k++){
    floatx4 wv = w4[k];
    floatx4 hh = h4[k];
    acc += wv[0]*hh[0] + wv[1]*hh[1] + wv[2]*hh[2] + wv[3]*hh[3];
  }
  out[(size_t)b*128 + c] = acc + bfc[c];
}

extern "C" void kernel_launch(void* const* d_in, const int* in_sizes, int n_in,
                              void* d_out, int out_size, void* d_ws, size_t ws_size,
                              hipStream_t stream)
{
  const float* x    = (const float*)d_in[0];
  const float* Wih0 = (const float*)d_in[1];
  const float* Whh0 = (const float*)d_in[2];
  const float* bih0 = (const float*)d_in[3];
  const float* bhh0 = (const float*)d_in[4];
  const float* Wih1 = (const float*)d_in[5];
  const float* Whh1 = (const float*)d_in[6];
  const float* bih1 = (const float*)d_in[7];
  const float* bhh1 = (const float*)d_in[8];
  const float* Wfc  = (const float*)d_in[9];
  const float* bfc  = (const float*)d_in[10];

  // zero only the flag pairs (ring slots written before first read; t=0 paths predicated)
  hipMemsetAsync(d_ws, 0, 4096, stream);

  lstm_pk<<<2*NBLK, 512, 0, stream>>>(x, Wih0, Whh0, bih0, bhh0, Wih1, Whh1, bih1, bhh1, (char*)d_ws);

  const float* h1f = (const float*)((char*)d_ws + (1<<20) + 2*(size_t)RING*B_*H_*2);
  fc_k<<<64, 128, 0, stream>>>(h1f, Wfc, bfc, (float*)d_out);
}